// Round 6
// baseline (3550.889 us; speedup 1.0000x reference)
//
#include <hip/hip_runtime.h>

typedef unsigned int u32;
typedef unsigned long long u64;
typedef unsigned char u8;

static constexpr int SORTN  = 65536; // pow2 >= max chosen pairs (<= N/2 + selfloops)
static constexpr int STILE  = 2048;  // bitonic LDS tile (2048 x 16B = 32 KiB)
static constexpr int NP     = 16;    // fused matching passes (pick[r-1] + min[r])
static constexpr int NHEAVY = 5;     // passes 1..NHEAVY use XCD-local nm8
static constexpr int NXCD   = 8;

// hardware XCD id (wave-uniform) [learn_hip m09]
__device__ __forceinline__ u32 xccid() {
  u32 x;
  asm volatile("s_getreg_b32 %0, hwreg(HW_REG_XCC_ID)" : "=s"(x));
  return x & (NXCD - 1);
}

// workgroup-scope u64 atomic min -> executes in the local XCD's L2 (no fabric
// round-trip). Each nm8 copy is touched by exactly one XCD; kernel-end flush
// publishes it for the next kernel's plain reads.
__device__ __forceinline__ void wmin64(u64* p, u64 v) {
  __hip_atomic_fetch_min(p, v, __ATOMIC_RELAXED, __HIP_MEMORY_SCOPE_WORKGROUP);
}

// monotonic float->uint mapping (ascending); bijective
__device__ __forceinline__ u32 ordf(float f) {
  u32 u = __float_as_uint(f);
  return (u & 0x80000000u) ? ~u : (u | 0x80000000u);
}
__device__ __forceinline__ float inv_ordf(u32 m) {
  return __uint_as_float((m & 0x80000000u) ? (m ^ 0x80000000u) : ~m);
}

__global__ __launch_bounds__(256)
void k_init(u32* m_ord, double* ssum, u8* matched, u64* nm8, u64* buf,
            float* scoreC, ulonglong2* sortbuf, u32* fcnt, u32* scalars,
            int N, int E) {
  int i = blockIdx.x * blockDim.x + threadIdx.x;
  if (i < N) {
    m_ord[i] = 0u; ssum[i] = 0.0; matched[i] = 0;
    scoreC[i] = 1.0f;   // singleton clusters keep score 1.0
  }
  if (i < 3 * N) buf[i] = ~0ull;
  if (i < NXCD * N) nm8[i] = ~0ull;
  if (i < SORTN) sortbuf[i] = make_ulonglong2(~0ull, ~0ull); // pad sorts to end
  if (i < 256)   fcnt[i] = 0u;
  if (i < 16)    scalars[i] = 0u;
  if (i == 0)    fcnt[0] = (u32)E;    // frontier 0 = all edges
}

// wave-per-node dual dot product: s_src = x.W[:256], s_dst = x.W[256:]
__global__ __launch_bounds__(256)
void k_dots(const float4* __restrict__ x4, const float4* __restrict__ W4,
            float* __restrict__ s_src, float* __restrict__ s_dst, int N) {
  int gt = blockIdx.x * blockDim.x + threadIdx.x;
  int w = gt >> 6, lane = gt & 63;
  if (w >= N) return;
  float4 xa = x4[(size_t)w * 64 + lane];
  float4 wa = W4[lane];
  float4 wb = W4[64 + lane];
  float pa = xa.x*wa.x + xa.y*wa.y + xa.z*wa.z + xa.w*wa.w;
  float pb = xa.x*wb.x + xa.y*wb.y + xa.z*wb.z + xa.w*wb.w;
  #pragma unroll
  for (int m = 32; m >= 1; m >>= 1) {
    pa += __shfl_xor(pa, m);
    pb += __shfl_xor(pb, m);
  }
  if (lane == 0) { s_src[w] = pa; s_dst[w] = pb; }
}

// segment max over dst (exact, via ordered-uint atomicMax)
__global__ __launch_bounds__(256)
void k_max(const int* __restrict__ src, const int* __restrict__ dst,
           const float* __restrict__ s_src, const float* __restrict__ s_dst,
           const float* __restrict__ bvec, u32* m_ord, int E) {
  int e = blockIdx.x * blockDim.x + threadIdx.x;
  if (e >= E) return;
  int d = dst[e];
  float r = s_src[src[e]] + s_dst[d] + bvec[0];
  atomicMax(&m_ord[d], ordf(r));
}

// exp(raw - max), f64 segment-sum (deterministic to f32 rounding)
__global__ __launch_bounds__(256)
void k_expsum(const int* __restrict__ src, const int* __restrict__ dst,
              const float* __restrict__ s_src, const float* __restrict__ s_dst,
              const float* __restrict__ bvec, const u32* __restrict__ m_ord,
              double* ssum, int E) {
  int e = blockIdx.x * blockDim.x + threadIdx.x;
  if (e >= E) return;
  int d = dst[e];
  float r = s_src[src[e]] + s_dst[d] + bvec[0];
  float ex = expf(r - inv_ordf(m_ord[d]));
  atomicAdd(&ssum[d], (double)ex);
}

// frontier entry: .x = key = (~ord(score))<<32 | edge_id  (asc == desc score,
// stable index tiebreak), .y = (src<<32)|dst. Round-0 min-build fused here
// via XCD-local workgroup-scope atomics.
__global__ __launch_bounds__(256)
void k_scorekey(const int* __restrict__ src, const int* __restrict__ dst,
                const float* __restrict__ s_src, const float* __restrict__ s_dst,
                const float* __restrict__ bvec, const u32* __restrict__ m_ord,
                const double* __restrict__ ssum,
                ulonglong2* __restrict__ front0, u64* nm8, int N, int E) {
  int e = blockIdx.x * blockDim.x + threadIdx.x;
  if (e >= E) return;
  u64* nmW = nm8 + (size_t)xccid() * N;
  int s = src[e], d = dst[e];
  float r = s_src[s] + s_dst[d] + bvec[0];
  float ex = expf(r - inv_ordf(m_ord[d]));
  float es = ex / (float)ssum[d] + 0.5f;
  u64 key = ((u64)(~ordf(es)) << 32) | (u32)e;
  u64 sd  = ((u64)(u32)s << 32) | (u32)d;
  front0[e] = make_ulonglong2(key, sd);
  wmin64(&nmW[s], key);
  if (d != s) wmin64(&nmW[d], key);
}

// fold 8 XCD-local copies -> bufOut, re-arm nm8 to ~0 for the next heavy pass
__global__ __launch_bounds__(256)
void k_merge(u64* nm8, u64* __restrict__ bufOut, int N) {
  int v = blockIdx.x * 256 + threadIdx.x;
  if (v >= N) return;
  u64 m = ~0ull;
  #pragma unroll
  for (int x = 0; x < NXCD; x++) {
    size_t idx = (size_t)x * N + v;
    u64 t = nm8[idx];
    if (t != ~0ull) { nm8[idx] = ~0ull; m = (t < m) ? t : m; }
  }
  bufOut[v] = m;
}

// fused matching pass R: pick against bufPrev (pass R-1's node-min), then
// atomicMin surviving keys into the current min target, compact survivors,
// and reset buf[(R+1)%3] entries the next pass will write.
// Staleness is benign: matched reads are only ever false-alive, so
// alive edges always survive & always contribute; dead keys delay a pick by
// one pass, never change the greedy fixed point.
template<int R, bool HEAVY>
__global__ __launch_bounds__(256)
void k_mstep(const ulonglong2* __restrict__ fin, const u32* __restrict__ cntp,
             const u64* __restrict__ bufPrev, u64* nmOut, u64* bufReset,
             u8* matched, ulonglong2* fout, u32* cntOut,
             ulonglong2* sortbuf, u32* scalars, int N) {
  __shared__ u32 wb[4];
  __shared__ u32 bbase;
  u32 cnt = *cntp;
  u64* nmW = nmOut;
  if (HEAVY) nmW += (size_t)xccid() * N;
  int tx = threadIdx.x, lane = tx & 63, wid = tx >> 6;
  for (u32 base = blockIdx.x * 256; base < cnt; base += gridDim.x * 256) {
    u32 gid = base + tx;
    ulonglong2 t = make_ulonglong2(0ull, 0ull);
    int s = 0, d = 0;
    bool pk = false, surv = false;
    if (gid < cnt) {
      t = fin[gid];
      s = (int)(t.y >> 32); d = (int)(u32)t.y;
      if (!(matched[s] | matched[d])) {
        pk = (bufPrev[s] == t.x) && (bufPrev[d] == t.x);
        surv = !pk;
      }
    }
    // picks: wave-aggregated append (order fixed by later sort)
    u64 pm = __ballot(pk);
    if (pm) {
      u32 pre = (u32)__popcll(pm & ((1ull << lane) - 1ull));
      int ldr = __ffsll((long long)pm) - 1;
      u32 pb = 0;
      if (lane == ldr) pb = atomicAdd(&scalars[0], (u32)__popcll(pm));
      pb = __shfl(pb, ldr);
      if (pk) { matched[s] = 1; matched[d] = 1; sortbuf[pb + pre] = t; }
    }
    // survivors: block-aggregated compaction + min-build + next-buf reset
    u64 sm = __ballot(surv);
    if (lane == 0) wb[wid] = (u32)__popcll(sm);
    __syncthreads();
    if (tx == 0) {
      u32 tt = wb[0] + wb[1] + wb[2] + wb[3];
      bbase = tt ? atomicAdd(cntOut, tt) : 0u;
    }
    __syncthreads();
    if (surv) {
      u32 woff = 0;
      for (int w = 0; w < wid; w++) woff += wb[w];
      u32 pre = (u32)__popcll(sm & ((1ull << lane) - 1ull));
      fout[bbase + woff + pre] = t;
      if (HEAVY) {
        wmin64(&nmW[s], t.x);
        if (d != s) wmin64(&nmW[d], t.x);
      } else {
        atomicMin(&nmW[s], t.x);
        if (d != s) atomicMin(&nmW[d], t.x);
      }
      bufReset[s] = ~0ull;
      if (d != s) bufReset[d] = ~0ull;
    }
    __syncthreads();
  }
}

// single-block finish: classic 2-phase rounds, workgroup-scope (local-L2)
// atomics; atomic-RMW reads of nm (L1 can't serve L2-atomic results).
__global__ __launch_bounds__(1024)
void k_mfinish(ulonglong2* fA, ulonglong2* fB, u8* matched, u64* nm,
               ulonglong2* sortbuf, const u32* __restrict__ cntp, u32* scalars) {
  __shared__ u32 sh_cnt;
  u32 cnt = *cntp;
  int tx = threadIdx.x;
  ulonglong2* fin = fA; ulonglong2* fout = fB;
  while (cnt > 0) {
    for (u32 i = tx; i < cnt; i += 1024) {
      u64 p = fin[i].y;
      nm[p >> 32] = ~0ull; nm[(u32)p] = ~0ull;
    }
    if (tx == 0) sh_cnt = 0;
    __syncthreads();
    for (u32 i = tx; i < cnt; i += 1024) {
      ulonglong2 t = fin[i];
      int s = (int)(t.y >> 32), d = (int)(u32)t.y;
      if (matched[s] | matched[d]) continue;
      wmin64(&nm[s], t.x);
      if (d != s) wmin64(&nm[d], t.x);
    }
    __syncthreads();
    for (u32 i = tx; i < cnt; i += 1024) {
      ulonglong2 t = fin[i];
      int s = (int)(t.y >> 32), d = (int)(u32)t.y;
      if (matched[s] | matched[d]) continue;
      u64 a = __hip_atomic_fetch_add(&nm[s], 0ull, __ATOMIC_RELAXED,
                                     __HIP_MEMORY_SCOPE_WORKGROUP);
      u64 b = (d == s) ? a
            : __hip_atomic_fetch_add(&nm[d], 0ull, __ATOMIC_RELAXED,
                                     __HIP_MEMORY_SCOPE_WORKGROUP);
      if (a == t.x && b == t.x) {
        matched[s] = 1; matched[d] = 1;
        u32 o = atomicAdd(&scalars[0], 1u);
        sortbuf[o] = t;
      } else {
        u32 o = atomicAdd(&sh_cnt, 1u);
        fout[o] = t;
      }
    }
    __syncthreads();
    cnt = sh_cnt;
    ulonglong2* tmp = fin; fin = fout; fout = tmp;
    __syncthreads();
  }
}

// ---- bitonic sort of SORTN {key,sd} pairs by .x, as plain launches ----
__global__ __launch_bounds__(256)
void k_sort1(ulonglong2* buf) {
  __shared__ ulonglong2 t[STILE];
  const int base = blockIdx.x * STILE;
  for (int i = threadIdx.x; i < STILE; i += 256) t[i] = buf[base + i];
  __syncthreads();
  for (int k = 2; k <= STILE; k <<= 1) {
    for (int j = k >> 1; j > 0; j >>= 1) {
      for (int i = threadIdx.x; i < STILE; i += 256) {
        int p = i ^ j;
        if (p > i) {
          bool dir = (((base + i) & k) == 0);
          ulonglong2 a = t[i], c = t[p];
          if ((a.x > c.x) == dir) { t[i] = c; t[p] = a; }
        }
      }
      __syncthreads();
    }
  }
  for (int i = threadIdx.x; i < STILE; i += 256) buf[base + i] = t[i];
}

__global__ __launch_bounds__(256)
void k_gpass(ulonglong2* buf, int j, int k) {
  int i = blockIdx.x * 256 + threadIdx.x;
  int p = i ^ j;
  if (p > i && p < SORTN) {
    bool dir = ((i & k) == 0);
    ulonglong2 a = buf[i], c = buf[p];
    if ((a.x > c.x) == dir) { buf[i] = c; buf[p] = a; }
  }
}

__global__ __launch_bounds__(256)
void k_sortl(ulonglong2* buf, int k) {
  __shared__ ulonglong2 t[STILE];
  const int base = blockIdx.x * STILE;
  const bool dir = ((base & k) == 0);   // uniform per tile (k > STILE)
  for (int i = threadIdx.x; i < STILE; i += 256) t[i] = buf[base + i];
  __syncthreads();
  for (int j = STILE >> 1; j > 0; j >>= 1) {
    for (int i = threadIdx.x; i < STILE; i += 256) {
      int p = i ^ j;
      if (p > i) {
        ulonglong2 a = t[i], c = t[p];
        if ((a.x > c.x) == dir) { t[i] = c; t[p] = a; }
      }
    }
    __syncthreads();
  }
  for (int i = threadIdx.x; i < STILE; i += 256) buf[base + i] = t[i];
}

// sorted position i == cluster id; score recovered bit-exactly from the key
__global__ __launch_bounds__(256)
void k_assign(const ulonglong2* __restrict__ buf,
              int* cluster, int* memA, int* memB, float* scoreC,
              const u32* __restrict__ scalars) {
  int i = blockIdx.x * blockDim.x + threadIdx.x;
  if (i >= (int)scalars[0]) return;
  ulonglong2 t = buf[i];
  int s = (int)(t.y >> 32), d = (int)(u32)t.y;
  cluster[s] = i; cluster[d] = i;
  scoreC[i] = inv_ordf(~(u32)(t.x >> 32));
  memA[i] = s;
  memB[i] = (s == d) ? -1 : d;   // self-loop: single member
}

// exclusive scan of unmatched nodes -> trailing singleton cluster ids
__global__ __launch_bounds__(256)
void k_scan1(const u8* __restrict__ matched, u32* partials, int N) {
  __shared__ u32 sh[256];
  int b = blockIdx.x, tx = threadIdx.x;
  int v0 = b * 1024 + tx * 4;
  u32 c = 0;
  #pragma unroll
  for (int q = 0; q < 4; q++) { int v = v0 + q; if (v < N && !matched[v]) c++; }
  sh[tx] = c; __syncthreads();
  for (int s = 128; s > 0; s >>= 1) { if (tx < s) sh[tx] += sh[tx + s]; __syncthreads(); }
  if (tx == 0) partials[b] = sh[0];
}

__global__ void k_scan2(const u32* partials, u32* partials2, u32* scalars, int NB) {
  if (blockIdx.x == 0 && threadIdx.x == 0) {
    u32 run = 0;
    for (int i = 0; i < NB; i++) { partials2[i] = run; run += partials[i]; }
    scalars[1] = run;                 // total unmatched
    scalars[2] = scalars[0] + run;    // num_clusters
  }
}

__global__ __launch_bounds__(256)
void k_scan3(const u8* __restrict__ matched, const u32* __restrict__ partials2,
             const u32* __restrict__ scalars, int* cluster, int* memA, int* memB, int N) {
  __shared__ u32 sh[256];
  int b = blockIdx.x, tx = threadIdx.x;
  int v0 = b * 1024 + tx * 4;
  u32 f[4]; u32 c = 0;
  #pragma unroll
  for (int q = 0; q < 4; q++) { int v = v0 + q; f[q] = (v < N && !matched[v]); c += f[q]; }
  sh[tx] = c; __syncthreads();
  for (int s = 1; s < 256; s <<= 1) {      // Hillis-Steele inclusive scan
    u32 x = sh[tx];
    u32 y = (tx >= s) ? sh[tx - s] : 0;
    __syncthreads();
    sh[tx] = x + y;
    __syncthreads();
  }
  u32 base = scalars[0] + partials2[b] + (sh[tx] - c);
  #pragma unroll
  for (int q = 0; q < 4; q++) {
    if (f[q]) {
      int v = v0 + q;
      int cc = (int)base++;
      cluster[v] = cc; memA[cc] = v; memB[cc] = -1;
    }
  }
}

// new_x: wave per output row; <=2 members per cluster; zero tail rows
__global__ __launch_bounds__(256)
void k_newx(const float4* __restrict__ x4, const int* __restrict__ memA,
            const int* __restrict__ memB, const float* __restrict__ scoreC,
            const u32* __restrict__ scalars, float4* __restrict__ out4, int N) {
  int gt = blockIdx.x * blockDim.x + threadIdx.x;
  int w = gt >> 6, lane = gt & 63;
  if (w >= N) return;
  int nc = (int)scalars[2];
  float4 o;
  if (w < nc) {
    int a = memA[w], b = memB[w];
    float s = scoreC[w];
    float4 va = x4[(size_t)a * 64 + lane];
    float ox = va.x, oy = va.y, oz = va.z, ow = va.w;
    if (b >= 0) {
      float4 vb = x4[(size_t)b * 64 + lane];
      ox += vb.x; oy += vb.y; oz += vb.z; ow += vb.w;
    }
    o = make_float4(ox * s, oy * s, oz * s, ow * s);
  } else {
    o = make_float4(0.f, 0.f, 0.f, 0.f);
  }
  out4[(size_t)w * 64 + lane] = o;
}

__global__ __launch_bounds__(256)
void k_remap(const int* __restrict__ ei, const int* __restrict__ cluster,
             float* __restrict__ outE, int twoE) {
  int i = blockIdx.x * blockDim.x + threadIdx.x;
  if (i < twoE) outE[i] = (float)cluster[ei[i]];
}

__global__ __launch_bounds__(256)
void k_tail(float* __restrict__ outB, const u32* __restrict__ scalars, int N) {
  int i = blockIdx.x * blockDim.x + threadIdx.x;
  if (i < N) outB[i] = 0.0f;                  // batch is all zeros
  if (i == 0) outB[N] = (float)scalars[2];    // num_clusters
}

// compile-time unrolled pass launcher (distinct symbols per pass for profiling)
template<int R>
static void launch_passes(ulonglong2* frontA, ulonglong2* frontB, u64* nm8,
                          u64* buf, u8* matched, ulonglong2* sortbuf,
                          u32* fcnt, u32* scalars, int N, int NB_E,
                          hipStream_t stream) {
  if constexpr (R <= NP) {
    constexpr bool HEAVY = (R <= NHEAVY);
    ulonglong2* fin  = (R & 1) ? frontA : frontB;
    ulonglong2* fout = (R & 1) ? frontB : frontA;
    const u64* bufPrev = buf + (size_t)((R - 1) % 3) * N;
    u64* bufCur   = buf + (size_t)(R % 3) * N;
    u64* bufReset = buf + (size_t)((R + 1) % 3) * N;
    u64* nmOut = HEAVY ? nm8 : bufCur;
    int nbr = NB_E >> (R - 1); if (nbr < 256) nbr = 256;
    k_mstep<R, HEAVY><<<nbr, 256, 0, stream>>>(fin, fcnt + R - 1, bufPrev, nmOut,
                                               bufReset, matched, fout, fcnt + R,
                                               sortbuf, scalars, N);
    if (HEAVY)
      k_merge<<<(N + 255) / 256, 256, 0, stream>>>(nm8, bufCur, N);
    launch_passes<R + 1>(frontA, frontB, nm8, buf, matched, sortbuf,
                         fcnt, scalars, N, NB_E, stream);
  }
}

extern "C" void kernel_launch(void* const* d_in, const int* in_sizes, int n_in,
                              void* d_out, int out_size, void* d_ws, size_t ws_size,
                              hipStream_t stream) {
  const float* x    = (const float*)d_in[0];
  const int*   ei   = (const int*)d_in[1];
  const float* W    = (const float*)d_in[3];
  const float* bvec = (const float*)d_in[4];
  int N = in_sizes[2];
  int E = in_sizes[1] / 2;

  // workspace carve-out (~65 MB)
  char* p = (char*)d_ws;
  auto alloc = [&](size_t bytes) { char* r = p; p += (bytes + 255) & ~(size_t)255; return r; };
  float*      s_src    = (float*)alloc((size_t)N * 4);
  float*      s_dst    = (float*)alloc((size_t)N * 4);
  u32*        m_ord    = (u32*)alloc((size_t)N * 4);
  double*     ssum     = (double*)alloc((size_t)N * 8);
  ulonglong2* frontA   = (ulonglong2*)alloc((size_t)E * 16);
  ulonglong2* frontB   = (ulonglong2*)alloc((size_t)E * 16);
  u8*         matched  = (u8*)alloc((size_t)N);
  u64*        nm8      = (u64*)alloc((size_t)NXCD * N * 8);
  u64*        buf      = (u64*)alloc((size_t)3 * N * 8);
  ulonglong2* sortbuf  = (ulonglong2*)alloc((size_t)SORTN * 16);
  int*        cluster  = (int*)alloc((size_t)N * 4);
  int*        memA     = (int*)alloc((size_t)N * 4);
  int*        memB     = (int*)alloc((size_t)N * 4);
  float*      scoreC   = (float*)alloc((size_t)N * 4);
  u32*        fcnt     = (u32*)alloc(1024);
  u32*        partials = (u32*)alloc(4096);
  u32*        partials2= (u32*)alloc(4096);
  u32*        scalars  = (u32*)alloc(256);
  (void)ws_size; (void)out_size; (void)n_in;

  const int* srcp = ei;
  const int* dstp = ei + E;
  float* out  = (float*)d_out;
  float* outX = out;
  float* outE = out + (size_t)N * 256;
  float* outB = outE + (size_t)2 * E;

  int NB_E = (E + 255) / 256;
  int cover = NXCD * N; if (cover < SORTN) cover = SORTN;
  k_init<<<(cover + 255) / 256, 256, 0, stream>>>(m_ord, ssum, matched, nm8, buf,
                                                  scoreC, sortbuf, fcnt, scalars, N, E);
  k_dots<<<((size_t)N * 64 + 255) / 256, 256, 0, stream>>>(
      (const float4*)x, (const float4*)W, s_src, s_dst, N);
  k_max<<<NB_E, 256, 0, stream>>>(srcp, dstp, s_src, s_dst, bvec, m_ord, E);
  k_expsum<<<NB_E, 256, 0, stream>>>(srcp, dstp, s_src, s_dst, bvec, m_ord, ssum, E);
  // scorekey also builds pass-0 node-min in nm8 (XCD-local)
  k_scorekey<<<NB_E, 256, 0, stream>>>(srcp, dstp, s_src, s_dst, bvec, m_ord, ssum,
                                       frontA, nm8, N, E);
  k_merge<<<(N + 255) / 256, 256, 0, stream>>>(nm8, buf, N);   // -> buf[0]

  launch_passes<1>(frontA, frontB, nm8, buf, matched, sortbuf, fcnt, scalars,
                   N, NB_E, stream);
  // NP even -> final survivors in frontA; mfinish uses buf[2] as scratch nm
  k_mfinish<<<1, 1024, 0, stream>>>(frontA, frontB, matched,
                                    buf + (size_t)((NP + 1) % 3) * N,
                                    sortbuf, fcnt + NP, scalars);

  // sort chosen edges (bitonic over SORTN, plain launches)
  k_sort1<<<SORTN / STILE, 256, 0, stream>>>(sortbuf);
  for (int k = STILE << 1; k <= SORTN; k <<= 1) {
    for (int j = k >> 1; j >= STILE; j >>= 1)
      k_gpass<<<SORTN / 256, 256, 0, stream>>>(sortbuf, j, k);
    k_sortl<<<SORTN / STILE, 256, 0, stream>>>(sortbuf, k);
  }

  k_assign<<<SORTN / 256, 256, 0, stream>>>(sortbuf, cluster, memA, memB, scoreC, scalars);
  int NB = (N + 1023) / 1024;
  k_scan1<<<NB, 256, 0, stream>>>(matched, partials, N);
  k_scan2<<<1, 64, 0, stream>>>(partials, partials2, scalars, NB);
  k_scan3<<<NB, 256, 0, stream>>>(matched, partials2, scalars, cluster, memA, memB, N);

  k_newx<<<((size_t)N * 64 + 255) / 256, 256, 0, stream>>>(
      (const float4*)x, memA, memB, scoreC, scalars, (float4*)outX, N);
  k_remap<<<(2 * E + 255) / 256, 256, 0, stream>>>(ei, cluster, outE, 2 * E);
  k_tail<<<(N + 255) / 256, 256, 0, stream>>>(outB, scalars, N);
}

// Round 7
// 1595.991 us; speedup vs baseline: 2.2249x; 2.2249x over previous
//
#include <hip/hip_runtime.h>

typedef unsigned int u32;
typedef unsigned long long u64;
typedef unsigned char u8;

static constexpr int SORTN = 65536; // pow2 >= max chosen pairs (<= N/2 + selfloops)
static constexpr int STILE = 2048;  // bitonic LDS tile (2048 x 16B = 32 KiB)
static constexpr int NR    = 12;    // two-phase matching rounds
static constexpr int NHEAVY= 3;     // rounds 0..NHEAVY-1 use XCD-local nm8
static constexpr int NXCD  = 8;

// hardware XCD id (wave-uniform) [learn_hip m09]
__device__ __forceinline__ u32 xccid() {
  u32 x;
  asm volatile("s_getreg_b32 %0, hwreg(HW_REG_XCC_ID)" : "=s"(x));
  return x & (NXCD - 1);
}

// workgroup-scope atomics -> execute in the local XCD's L2 (no memory-side
// fabric round-trip). Each per-XCD copy is touched by one XCD only; the
// kernel-end flush publishes it for the next kernel's plain reads.
__device__ __forceinline__ void wmin64(u64* p, u64 v) {
  __hip_atomic_fetch_min(p, v, __ATOMIC_RELAXED, __HIP_MEMORY_SCOPE_WORKGROUP);
}
__device__ __forceinline__ void wmax32(u32* p, u32 v) {
  __hip_atomic_fetch_max(p, v, __ATOMIC_RELAXED, __HIP_MEMORY_SCOPE_WORKGROUP);
}
__device__ __forceinline__ void waddf64(double* p, double v) {
  __hip_atomic_fetch_add(p, v, __ATOMIC_RELAXED, __HIP_MEMORY_SCOPE_WORKGROUP);
}

// monotonic float->uint mapping (ascending); bijective
__device__ __forceinline__ u32 ordf(float f) {
  u32 u = __float_as_uint(f);
  return (u & 0x80000000u) ? ~u : (u | 0x80000000u);
}
__device__ __forceinline__ float inv_ordf(u32 m) {
  return __uint_as_float((m & 0x80000000u) ? (m ^ 0x80000000u) : ~m);
}

__global__ __launch_bounds__(256)
void k_init(u32* m_ord, u32* m8, double* ssum, double* ss8, u8* matched,
            u64* node_min, u64* nm8, float* scoreC, ulonglong2* sortbuf,
            u32* fcnt, u32* scalars, int N, int E) {
  int i = blockIdx.x * blockDim.x + threadIdx.x;
  if (i < N) { m_ord[i] = 0u; ssum[i] = 0.0; matched[i] = 0; scoreC[i] = 1.0f; }
  if (i < 2 * N) node_min[i] = ~0ull;
  if (i < NXCD * N) { nm8[i] = ~0ull; m8[i] = 0u; ss8[i] = 0.0; }
  if (i < SORTN) sortbuf[i] = make_ulonglong2(~0ull, ~0ull); // pad sorts to end
  if (i < 256)   fcnt[i] = 0u;
  if (i < 16)    scalars[i] = 0u;
  if (i == 0)    fcnt[0] = (u32)E;    // frontier 0 = all edges
}

// wave-per-node dual dot product: s_src = x.W[:256], s_dst = x.W[256:]
__global__ __launch_bounds__(256)
void k_dots(const float4* __restrict__ x4, const float4* __restrict__ W4,
            float* __restrict__ s_src, float* __restrict__ s_dst, int N) {
  int gt = blockIdx.x * blockDim.x + threadIdx.x;
  int w = gt >> 6, lane = gt & 63;
  if (w >= N) return;
  float4 xa = x4[(size_t)w * 64 + lane];
  float4 wa = W4[lane];
  float4 wb = W4[64 + lane];
  float pa = xa.x*wa.x + xa.y*wa.y + xa.z*wa.z + xa.w*wa.w;
  float pb = xa.x*wb.x + xa.y*wb.y + xa.z*wb.z + xa.w*wb.w;
  #pragma unroll
  for (int m = 32; m >= 1; m >>= 1) {
    pa += __shfl_xor(pa, m);
    pb += __shfl_xor(pb, m);
  }
  if (lane == 0) { s_src[w] = pa; s_dst[w] = pb; }
}

// segment max over dst, XCD-local copies (exact: max is order-free)
__global__ __launch_bounds__(256)
void k_max8(const int* __restrict__ src, const int* __restrict__ dst,
            const float* __restrict__ s_src, const float* __restrict__ s_dst,
            const float* __restrict__ bvec, u32* m8, int N, int E) {
  int e = blockIdx.x * blockDim.x + threadIdx.x;
  if (e >= E) return;
  u32* mW = m8 + (size_t)xccid() * N;
  int d = dst[e];
  float r = s_src[src[e]] + s_dst[d] + bvec[0];
  wmax32(&mW[d], ordf(r));
}

__global__ __launch_bounds__(256)
void k_maxmerge(const u32* __restrict__ m8, u32* __restrict__ m_ord, int N) {
  int v = blockIdx.x * 256 + threadIdx.x;
  if (v >= N) return;
  u32 m = 0u;
  #pragma unroll
  for (int x = 0; x < NXCD; x++) {
    u32 t = m8[(size_t)x * N + v];
    m = (t > m) ? t : m;
  }
  m_ord[v] = m;
}

// exp(raw - max), f64 segment-sum in XCD-local copies (order noise ~1e-16,
// vanishes on f32 round; merge folds in fixed order)
__global__ __launch_bounds__(256)
void k_expsum8(const int* __restrict__ src, const int* __restrict__ dst,
               const float* __restrict__ s_src, const float* __restrict__ s_dst,
               const float* __restrict__ bvec, const u32* __restrict__ m_ord,
               double* ss8, int N, int E) {
  int e = blockIdx.x * blockDim.x + threadIdx.x;
  if (e >= E) return;
  double* sW = ss8 + (size_t)xccid() * N;
  int d = dst[e];
  float r = s_src[src[e]] + s_dst[d] + bvec[0];
  float ex = expf(r - inv_ordf(m_ord[d]));
  waddf64(&sW[d], (double)ex);
}

__global__ __launch_bounds__(256)
void k_ssmerge(const double* __restrict__ ss8, double* __restrict__ ssum, int N) {
  int v = blockIdx.x * 256 + threadIdx.x;
  if (v >= N) return;
  double s = 0.0;
  #pragma unroll
  for (int x = 0; x < NXCD; x++) s += ss8[(size_t)x * N + v];
  ssum[v] = s;
}

// frontier entry: .x = key = (~ord(score))<<32 | edge_id  (asc == desc score,
// stable index tiebreak), .y = (src<<32)|dst. Round-0 min-build fused here
// (complete before k_mpick<0> runs -> exact two-phase semantics).
__global__ __launch_bounds__(256)
void k_scorekey(const int* __restrict__ src, const int* __restrict__ dst,
                const float* __restrict__ s_src, const float* __restrict__ s_dst,
                const float* __restrict__ bvec, const u32* __restrict__ m_ord,
                const double* __restrict__ ssum,
                ulonglong2* __restrict__ front0, u64* nm8, int N, int E) {
  int e = blockIdx.x * blockDim.x + threadIdx.x;
  if (e >= E) return;
  u64* nmW = nm8 + (size_t)xccid() * N;
  int s = src[e], d = dst[e];
  float r = s_src[s] + s_dst[d] + bvec[0];
  float ex = expf(r - inv_ordf(m_ord[d]));
  float es = ex / (float)ssum[d] + 0.5f;
  u64 key = ((u64)(~ordf(es)) << 32) | (u32)e;
  u64 sd  = ((u64)(u32)s << 32) | (u32)d;
  front0[e] = make_ulonglong2(key, sd);
  wmin64(&nmW[s], key);
  if (d != s) wmin64(&nmW[d], key);
}

// fold 8 XCD-local copies -> nmOut (writes ALL N entries), re-arm nm8 to ~0
__global__ __launch_bounds__(256)
void k_merge(u64* nm8, u64* __restrict__ nmOut, int N) {
  int v = blockIdx.x * 256 + threadIdx.x;
  if (v >= N) return;
  u64 m = ~0ull;
  #pragma unroll
  for (int x = 0; x < NXCD; x++) {
    size_t idx = (size_t)x * N + v;
    u64 t = nm8[idx];
    if (t != ~0ull) { nm8[idx] = ~0ull; m = (t < m) ? t : m; }
  }
  nmOut[v] = m;
}

// min phase (heavy): XCD-local copies, local-L2 RMW
template<int R>
__global__ __launch_bounds__(256)
void k_mmin_h(const ulonglong2* __restrict__ fin, const u32* __restrict__ cntp,
              const u8* __restrict__ matched, u64* nm8, int N) {
  u32 cnt = *cntp;
  u64* nmW = nm8 + (size_t)xccid() * N;
  u32 nth = gridDim.x * 256;
  for (u32 i = blockIdx.x * 256 + threadIdx.x; i < cnt; i += nth) {
    ulonglong2 t = fin[i];
    int s = (int)(t.y >> 32), d = (int)(u32)t.y;
    if (matched[s] | matched[d]) continue;
    wmin64(&nmW[s], t.x);
    if (d != s) wmin64(&nmW[d], t.x);
  }
}

// min phase (light): small frontier, device-scope atomics are fine
template<int R>
__global__ __launch_bounds__(256)
void k_mmin_l(const ulonglong2* __restrict__ fin, const u32* __restrict__ cntp,
              const u8* __restrict__ matched, u64* nm) {
  u32 cnt = *cntp;
  u32 nth = gridDim.x * 256;
  for (u32 i = blockIdx.x * 256 + threadIdx.x; i < cnt; i += nth) {
    ulonglong2 t = fin[i];
    int s = (int)(t.y >> 32), d = (int)(u32)t.y;
    if (matched[s] | matched[d]) continue;
    atomicMin(&nm[s], t.x);
    if (d != s) atomicMin(&nm[d], t.x);
  }
}

// pick phase: min at BOTH endpoints -> matched (vertex-disjoint, keys unique);
// survivors compacted (1 atomic/block) + survivor-only reset of next nm buffer.
template<int R>
__global__ __launch_bounds__(256)
void k_mpick(const ulonglong2* __restrict__ fin, const u32* __restrict__ cntp,
             const u64* __restrict__ nm, u64* nmNext, u8* matched,
             ulonglong2* fout, u32* cntOut, ulonglong2* sortbuf, u32* scalars) {
  __shared__ u32 wb[4];
  __shared__ u32 bbase;
  u32 cnt = *cntp;
  int tx = threadIdx.x, lane = tx & 63, wid = tx >> 6;
  for (u32 base = blockIdx.x * 256; base < cnt; base += gridDim.x * 256) {
    u32 gid = base + tx;
    ulonglong2 t = make_ulonglong2(0ull, 0ull);
    int s = 0, d = 0;
    bool pk = false, surv = false;
    if (gid < cnt) {
      t = fin[gid];
      s = (int)(t.y >> 32); d = (int)(u32)t.y;
      if (!(matched[s] | matched[d])) {
        pk = (nm[s] == t.x) && (nm[d] == t.x);
        surv = !pk;
      }
    }
    // picks: wave-aggregated append (order fixed by later sort)
    u64 pm = __ballot(pk);
    if (pm) {
      u32 pre = (u32)__popcll(pm & ((1ull << lane) - 1ull));
      int ldr = __ffsll((long long)pm) - 1;
      u32 pb = 0;
      if (lane == ldr) pb = atomicAdd(&scalars[0], (u32)__popcll(pm));
      pb = __shfl(pb, ldr);
      if (pk) { matched[s] = 1; matched[d] = 1; sortbuf[pb + pre] = t; }
    }
    // survivors: block-aggregated compaction + next-round nm reset
    u64 sm = __ballot(surv);
    if (lane == 0) wb[wid] = (u32)__popcll(sm);
    __syncthreads();
    if (tx == 0) {
      u32 tt = wb[0] + wb[1] + wb[2] + wb[3];
      bbase = tt ? atomicAdd(cntOut, tt) : 0u;
    }
    __syncthreads();
    if (surv) {
      u32 woff = 0;
      for (int w = 0; w < wid; w++) woff += wb[w];
      u32 pre = (u32)__popcll(sm & ((1ull << lane) - 1ull));
      fout[bbase + woff + pre] = t;
      nmNext[s] = ~0ull;
      if (d != s) nmNext[d] = ~0ull;
    }
    __syncthreads();
  }
}

// single-block finish: two-phase rounds, workgroup-scope (local-L2) atomics;
// atomic-RMW reads of nm (L1 can't serve L2-atomic results).
__global__ __launch_bounds__(1024)
void k_mfinish(ulonglong2* fA, ulonglong2* fB, u8* matched, u64* nm,
               ulonglong2* sortbuf, const u32* __restrict__ cntp, u32* scalars) {
  __shared__ u32 sh_cnt;
  u32 cnt = *cntp;
  int tx = threadIdx.x;
  ulonglong2* fin = fA; ulonglong2* fout = fB;
  while (cnt > 0) {
    for (u32 i = tx; i < cnt; i += 1024) {
      u64 p = fin[i].y;
      nm[p >> 32] = ~0ull; nm[(u32)p] = ~0ull;
    }
    if (tx == 0) sh_cnt = 0;
    __syncthreads();
    for (u32 i = tx; i < cnt; i += 1024) {
      ulonglong2 t = fin[i];
      int s = (int)(t.y >> 32), d = (int)(u32)t.y;
      if (matched[s] | matched[d]) continue;
      wmin64(&nm[s], t.x);
      if (d != s) wmin64(&nm[d], t.x);
    }
    __syncthreads();
    for (u32 i = tx; i < cnt; i += 1024) {
      ulonglong2 t = fin[i];
      int s = (int)(t.y >> 32), d = (int)(u32)t.y;
      if (matched[s] | matched[d]) continue;
      u64 a = __hip_atomic_fetch_add(&nm[s], 0ull, __ATOMIC_RELAXED,
                                     __HIP_MEMORY_SCOPE_WORKGROUP);
      u64 b = (d == s) ? a
            : __hip_atomic_fetch_add(&nm[d], 0ull, __ATOMIC_RELAXED,
                                     __HIP_MEMORY_SCOPE_WORKGROUP);
      if (a == t.x && b == t.x) {
        matched[s] = 1; matched[d] = 1;
        u32 o = atomicAdd(&scalars[0], 1u);
        sortbuf[o] = t;
      } else {
        u32 o = atomicAdd(&sh_cnt, 1u);
        fout[o] = t;
      }
    }
    __syncthreads();
    cnt = sh_cnt;
    ulonglong2* tmp = fin; fin = fout; fout = tmp;
    __syncthreads();
  }
}

// ---- bitonic sort of SORTN {key,sd} pairs by .x, as plain launches ----
__global__ __launch_bounds__(256)
void k_sort1(ulonglong2* buf) {
  __shared__ ulonglong2 t[STILE];
  const int base = blockIdx.x * STILE;
  for (int i = threadIdx.x; i < STILE; i += 256) t[i] = buf[base + i];
  __syncthreads();
  for (int k = 2; k <= STILE; k <<= 1) {
    for (int j = k >> 1; j > 0; j >>= 1) {
      for (int i = threadIdx.x; i < STILE; i += 256) {
        int p = i ^ j;
        if (p > i) {
          bool dir = (((base + i) & k) == 0);
          ulonglong2 a = t[i], c = t[p];
          if ((a.x > c.x) == dir) { t[i] = c; t[p] = a; }
        }
      }
      __syncthreads();
    }
  }
  for (int i = threadIdx.x; i < STILE; i += 256) buf[base + i] = t[i];
}

__global__ __launch_bounds__(256)
void k_gpass(ulonglong2* buf, int j, int k) {
  int i = blockIdx.x * 256 + threadIdx.x;
  int p = i ^ j;
  if (p > i && p < SORTN) {
    bool dir = ((i & k) == 0);
    ulonglong2 a = buf[i], c = buf[p];
    if ((a.x > c.x) == dir) { buf[i] = c; buf[p] = a; }
  }
}

__global__ __launch_bounds__(256)
void k_sortl(ulonglong2* buf, int k) {
  __shared__ ulonglong2 t[STILE];
  const int base = blockIdx.x * STILE;
  const bool dir = ((base & k) == 0);   // uniform per tile (k > STILE)
  for (int i = threadIdx.x; i < STILE; i += 256) t[i] = buf[base + i];
  __syncthreads();
  for (int j = STILE >> 1; j > 0; j >>= 1) {
    for (int i = threadIdx.x; i < STILE; i += 256) {
      int p = i ^ j;
      if (p > i) {
        ulonglong2 a = t[i], c = t[p];
        if ((a.x > c.x) == dir) { t[i] = c; t[p] = a; }
      }
    }
    __syncthreads();
  }
  for (int i = threadIdx.x; i < STILE; i += 256) buf[base + i] = t[i];
}

// sorted position i == cluster id; score recovered bit-exactly from the key
__global__ __launch_bounds__(256)
void k_assign(const ulonglong2* __restrict__ buf,
              int* cluster, int* memA, int* memB, float* scoreC,
              const u32* __restrict__ scalars) {
  int i = blockIdx.x * blockDim.x + threadIdx.x;
  if (i >= (int)scalars[0]) return;
  ulonglong2 t = buf[i];
  int s = (int)(t.y >> 32), d = (int)(u32)t.y;
  cluster[s] = i; cluster[d] = i;
  scoreC[i] = inv_ordf(~(u32)(t.x >> 32));
  memA[i] = s;
  memB[i] = (s == d) ? -1 : d;   // self-loop: single member
}

// exclusive scan of unmatched nodes -> trailing singleton cluster ids
__global__ __launch_bounds__(256)
void k_scan1(const u8* __restrict__ matched, u32* partials, int N) {
  __shared__ u32 sh[256];
  int b = blockIdx.x, tx = threadIdx.x;
  int v0 = b * 1024 + tx * 4;
  u32 c = 0;
  #pragma unroll
  for (int q = 0; q < 4; q++) { int v = v0 + q; if (v < N && !matched[v]) c++; }
  sh[tx] = c; __syncthreads();
  for (int s = 128; s > 0; s >>= 1) { if (tx < s) sh[tx] += sh[tx + s]; __syncthreads(); }
  if (tx == 0) partials[b] = sh[0];
}

__global__ void k_scan2(const u32* partials, u32* partials2, u32* scalars, int NB) {
  if (blockIdx.x == 0 && threadIdx.x == 0) {
    u32 run = 0;
    for (int i = 0; i < NB; i++) { partials2[i] = run; run += partials[i]; }
    scalars[1] = run;                 // total unmatched
    scalars[2] = scalars[0] + run;    // num_clusters
  }
}

__global__ __launch_bounds__(256)
void k_scan3(const u8* __restrict__ matched, const u32* __restrict__ partials2,
             const u32* __restrict__ scalars, int* cluster, int* memA, int* memB, int N) {
  __shared__ u32 sh[256];
  int b = blockIdx.x, tx = threadIdx.x;
  int v0 = b * 1024 + tx * 4;
  u32 f[4]; u32 c = 0;
  #pragma unroll
  for (int q = 0; q < 4; q++) { int v = v0 + q; f[q] = (v < N && !matched[v]); c += f[q]; }
  sh[tx] = c; __syncthreads();
  for (int s = 1; s < 256; s <<= 1) {      // Hillis-Steele inclusive scan
    u32 x = sh[tx];
    u32 y = (tx >= s) ? sh[tx - s] : 0;
    __syncthreads();
    sh[tx] = x + y;
    __syncthreads();
  }
  u32 base = scalars[0] + partials2[b] + (sh[tx] - c);
  #pragma unroll
  for (int q = 0; q < 4; q++) {
    if (f[q]) {
      int v = v0 + q;
      int cc = (int)base++;
      cluster[v] = cc; memA[cc] = v; memB[cc] = -1;
    }
  }
}

// new_x: wave per output row; <=2 members per cluster; zero tail rows
__global__ __launch_bounds__(256)
void k_newx(const float4* __restrict__ x4, const int* __restrict__ memA,
            const int* __restrict__ memB, const float* __restrict__ scoreC,
            const u32* __restrict__ scalars, float4* __restrict__ out4, int N) {
  int gt = blockIdx.x * blockDim.x + threadIdx.x;
  int w = gt >> 6, lane = gt & 63;
  if (w >= N) return;
  int nc = (int)scalars[2];
  float4 o;
  if (w < nc) {
    int a = memA[w], b = memB[w];
    float s = scoreC[w];
    float4 va = x4[(size_t)a * 64 + lane];
    float ox = va.x, oy = va.y, oz = va.z, ow = va.w;
    if (b >= 0) {
      float4 vb = x4[(size_t)b * 64 + lane];
      ox += vb.x; oy += vb.y; oz += vb.z; ow += vb.w;
    }
    o = make_float4(ox * s, oy * s, oz * s, ow * s);
  } else {
    o = make_float4(0.f, 0.f, 0.f, 0.f);
  }
  out4[(size_t)w * 64 + lane] = o;
}

__global__ __launch_bounds__(256)
void k_remap(const int* __restrict__ ei, const int* __restrict__ cluster,
             float* __restrict__ outE, int twoE) {
  int i = blockIdx.x * blockDim.x + threadIdx.x;
  if (i < twoE) outE[i] = (float)cluster[ei[i]];
}

__global__ __launch_bounds__(256)
void k_tail(float* __restrict__ outB, const u32* __restrict__ scalars, int N) {
  int i = blockIdx.x * blockDim.x + threadIdx.x;
  if (i < N) outB[i] = 0.0f;                  // batch is all zeros
  if (i == 0) outB[N] = (float)scalars[2];    // num_clusters
}

// compile-time unrolled round launcher (distinct symbols per round)
template<int R>
static void launch_rounds(ulonglong2* frontA, ulonglong2* frontB, u64* nm8,
                          u64* node_min, u8* matched, ulonglong2* sortbuf,
                          u32* fcnt, u32* scalars, int N, int NB_E,
                          hipStream_t stream) {
  if constexpr (R < NR) {
    ulonglong2* fin  = (R & 1) ? frontB : frontA;
    ulonglong2* fout = (R & 1) ? frontA : frontB;
    u64* nm  = node_min + (size_t)(R & 1) * N;
    u64* nmN = node_min + (size_t)((R & 1) ^ 1) * N;
    int nbr = NB_E >> R; if (nbr < 256) nbr = 256;
    if constexpr (R == 0) {
      // round-0 min map already built by k_scorekey + k_merge
    } else if constexpr (R < NHEAVY) {
      k_mmin_h<R><<<nbr, 256, 0, stream>>>(fin, fcnt + R, matched, nm8, N);
      k_merge<<<(N + 255) / 256, 256, 0, stream>>>(nm8, nm, N);
    } else {
      k_mmin_l<R><<<nbr, 256, 0, stream>>>(fin, fcnt + R, matched, nm);
    }
    k_mpick<R><<<nbr, 256, 0, stream>>>(fin, fcnt + R, nm, nmN, matched,
                                        fout, fcnt + R + 1, sortbuf, scalars);
    launch_rounds<R + 1>(frontA, frontB, nm8, node_min, matched, sortbuf,
                         fcnt, scalars, N, NB_E, stream);
  }
}

extern "C" void kernel_launch(void* const* d_in, const int* in_sizes, int n_in,
                              void* d_out, int out_size, void* d_ws, size_t ws_size,
                              hipStream_t stream) {
  const float* x    = (const float*)d_in[0];
  const int*   ei   = (const int*)d_in[1];
  const float* W    = (const float*)d_in[3];
  const float* bvec = (const float*)d_in[4];
  int N = in_sizes[2];
  int E = in_sizes[1] / 2;

  // workspace carve-out (~75 MB)
  char* p = (char*)d_ws;
  auto alloc = [&](size_t bytes) { char* r = p; p += (bytes + 255) & ~(size_t)255; return r; };
  float*      s_src    = (float*)alloc((size_t)N * 4);
  float*      s_dst    = (float*)alloc((size_t)N * 4);
  u32*        m_ord    = (u32*)alloc((size_t)N * 4);
  u32*        m8       = (u32*)alloc((size_t)NXCD * N * 4);
  double*     ssum     = (double*)alloc((size_t)N * 8);
  double*     ss8      = (double*)alloc((size_t)NXCD * N * 8);
  ulonglong2* frontA   = (ulonglong2*)alloc((size_t)E * 16);
  ulonglong2* frontB   = (ulonglong2*)alloc((size_t)E * 16);
  u8*         matched  = (u8*)alloc((size_t)N);
  u64*        node_min = (u64*)alloc((size_t)2 * N * 8);
  u64*        nm8      = (u64*)alloc((size_t)NXCD * N * 8);
  ulonglong2* sortbuf  = (ulonglong2*)alloc((size_t)SORTN * 16);
  int*        cluster  = (int*)alloc((size_t)N * 4);
  int*        memA     = (int*)alloc((size_t)N * 4);
  int*        memB     = (int*)alloc((size_t)N * 4);
  float*      scoreC   = (float*)alloc((size_t)N * 4);
  u32*        fcnt     = (u32*)alloc(1024);
  u32*        partials = (u32*)alloc(4096);
  u32*        partials2= (u32*)alloc(4096);
  u32*        scalars  = (u32*)alloc(256);
  (void)ws_size; (void)out_size; (void)n_in;

  const int* srcp = ei;
  const int* dstp = ei + E;
  float* out  = (float*)d_out;
  float* outX = out;
  float* outE = out + (size_t)N * 256;
  float* outB = outE + (size_t)2 * E;

  int NB_E = (E + 255) / 256;
  int cover = NXCD * N; if (cover < SORTN) cover = SORTN;
  k_init<<<(cover + 255) / 256, 256, 0, stream>>>(m_ord, m8, ssum, ss8, matched,
                                                  node_min, nm8, scoreC, sortbuf,
                                                  fcnt, scalars, N, E);
  k_dots<<<((size_t)N * 64 + 255) / 256, 256, 0, stream>>>(
      (const float4*)x, (const float4*)W, s_src, s_dst, N);
  k_max8<<<NB_E, 256, 0, stream>>>(srcp, dstp, s_src, s_dst, bvec, m8, N, E);
  k_maxmerge<<<(N + 255) / 256, 256, 0, stream>>>(m8, m_ord, N);
  k_expsum8<<<NB_E, 256, 0, stream>>>(srcp, dstp, s_src, s_dst, bvec, m_ord, ss8, N, E);
  k_ssmerge<<<(N + 255) / 256, 256, 0, stream>>>(ss8, ssum, N);
  // scorekey also builds round-0 node-min in nm8 (XCD-local)
  k_scorekey<<<NB_E, 256, 0, stream>>>(srcp, dstp, s_src, s_dst, bvec, m_ord, ssum,
                                       frontA, nm8, N, E);
  k_merge<<<(N + 255) / 256, 256, 0, stream>>>(nm8, node_min, N);  // -> buffer 0

  launch_rounds<0>(frontA, frontB, nm8, node_min, matched, sortbuf, fcnt, scalars,
                   N, NB_E, stream);
  // NR even -> final survivors in frontA; mfinish uses buffer 0 (self-reset)
  k_mfinish<<<1, 1024, 0, stream>>>(frontA, frontB, matched, node_min,
                                    sortbuf, fcnt + NR, scalars);

  // sort chosen edges (bitonic over SORTN, plain launches)
  k_sort1<<<SORTN / STILE, 256, 0, stream>>>(sortbuf);
  for (int k = STILE << 1; k <= SORTN; k <<= 1) {
    for (int j = k >> 1; j >= STILE; j >>= 1)
      k_gpass<<<SORTN / 256, 256, 0, stream>>>(sortbuf, j, k);
    k_sortl<<<SORTN / STILE, 256, 0, stream>>>(sortbuf, k);
  }

  k_assign<<<SORTN / 256, 256, 0, stream>>>(sortbuf, cluster, memA, memB, scoreC, scalars);
  int NB = (N + 1023) / 1024;
  k_scan1<<<NB, 256, 0, stream>>>(matched, partials, N);
  k_scan2<<<1, 64, 0, stream>>>(partials, partials2, scalars, NB);
  k_scan3<<<NB, 256, 0, stream>>>(matched, partials2, scalars, cluster, memA, memB, N);

  k_newx<<<((size_t)N * 64 + 255) / 256, 256, 0, stream>>>(
      (const float4*)x, memA, memB, scoreC, scalars, (float4*)outX, N);
  k_remap<<<(2 * E + 255) / 256, 256, 0, stream>>>(ei, cluster, outE, 2 * E);
  k_tail<<<(N + 255) / 256, 256, 0, stream>>>(outB, scalars, N);
}

// Round 8
// 1470.388 us; speedup vs baseline: 2.4149x; 1.0854x over previous
//
#include <hip/hip_runtime.h>

typedef unsigned int u32;
typedef unsigned long long u64;
typedef unsigned char u8;

static constexpr int SORTN = 65536; // pow2 >= max chosen pairs (<= N/2 + selfloops)
static constexpr int STILE = 2048;  // bitonic LDS tile (2048 x 16B = 32 KiB)
static constexpr int NR    = 28;    // two-phase matching rounds
static constexpr int NHEAVY= 3;     // rounds 0..NHEAVY-1 use XCD-local nm8
static constexpr int NXCD  = 8;

// hardware XCD id (wave-uniform) [learn_hip m09]
__device__ __forceinline__ u32 xccid() {
  u32 x;
  asm volatile("s_getreg_b32 %0, hwreg(HW_REG_XCC_ID)" : "=s"(x));
  return x & (NXCD - 1);
}

// workgroup-scope atomics -> execute in the local XCD's L2 (no memory-side
// fabric round-trip). Each per-XCD copy is touched by one XCD only; the
// kernel-end flush publishes it for the next kernel's plain reads.
__device__ __forceinline__ void wmin64(u64* p, u64 v) {
  __hip_atomic_fetch_min(p, v, __ATOMIC_RELAXED, __HIP_MEMORY_SCOPE_WORKGROUP);
}
__device__ __forceinline__ void wmax32(u32* p, u32 v) {
  __hip_atomic_fetch_max(p, v, __ATOMIC_RELAXED, __HIP_MEMORY_SCOPE_WORKGROUP);
}
__device__ __forceinline__ void waddf64(double* p, double v) {
  __hip_atomic_fetch_add(p, v, __ATOMIC_RELAXED, __HIP_MEMORY_SCOPE_WORKGROUP);
}

// monotonic float->uint mapping (ascending); bijective
__device__ __forceinline__ u32 ordf(float f) {
  u32 u = __float_as_uint(f);
  return (u & 0x80000000u) ? ~u : (u | 0x80000000u);
}
__device__ __forceinline__ float inv_ordf(u32 m) {
  return __uint_as_float((m & 0x80000000u) ? (m ^ 0x80000000u) : ~m);
}

__global__ __launch_bounds__(256)
void k_init(u32* m_ord, u32* m8, double* ssum, double* ss8, u8* matched,
            u64* node_min, u64* nm8, float* scoreC, ulonglong2* sortbuf,
            u32* fcnt, u32* scalars, int N, int E) {
  int i = blockIdx.x * blockDim.x + threadIdx.x;
  if (i < N) { m_ord[i] = 0u; ssum[i] = 0.0; matched[i] = 0; scoreC[i] = 1.0f; }
  if (i < 2 * N) node_min[i] = ~0ull;
  if (i < NXCD * N) { nm8[i] = ~0ull; m8[i] = 0u; ss8[i] = 0.0; }
  if (i < SORTN) sortbuf[i] = make_ulonglong2(~0ull, ~0ull); // pad sorts to end
  if (i < 256)   fcnt[i] = 0u;
  if (i < 16)    scalars[i] = 0u;
  if (i == 0)    fcnt[0] = (u32)E;    // frontier 0 = all edges
}

// wave-per-node dual dot product: s_src = x.W[:256], s_dst = x.W[256:]
__global__ __launch_bounds__(256)
void k_dots(const float4* __restrict__ x4, const float4* __restrict__ W4,
            float* __restrict__ s_src, float* __restrict__ s_dst, int N) {
  int gt = blockIdx.x * blockDim.x + threadIdx.x;
  int w = gt >> 6, lane = gt & 63;
  if (w >= N) return;
  float4 xa = x4[(size_t)w * 64 + lane];
  float4 wa = W4[lane];
  float4 wb = W4[64 + lane];
  float pa = xa.x*wa.x + xa.y*wa.y + xa.z*wa.z + xa.w*wa.w;
  float pb = xa.x*wb.x + xa.y*wb.y + xa.z*wb.z + xa.w*wb.w;
  #pragma unroll
  for (int m = 32; m >= 1; m >>= 1) {
    pa += __shfl_xor(pa, m);
    pb += __shfl_xor(pb, m);
  }
  if (lane == 0) { s_src[w] = pa; s_dst[w] = pb; }
}

// segment max over dst, XCD-local copies; also caches raw edge score
__global__ __launch_bounds__(256)
void k_max8(const int* __restrict__ src, const int* __restrict__ dst,
            const float* __restrict__ s_src, const float* __restrict__ s_dst,
            const float* __restrict__ bvec, u32* m8, float* __restrict__ raw,
            int N, int E) {
  int e = blockIdx.x * blockDim.x + threadIdx.x;
  if (e >= E) return;
  u32* mW = m8 + (size_t)xccid() * N;
  int d = dst[e];
  float r = s_src[src[e]] + s_dst[d] + bvec[0];
  raw[e] = r;
  wmax32(&mW[d], ordf(r));
}

__global__ __launch_bounds__(256)
void k_maxmerge(const u32* __restrict__ m8, u32* __restrict__ m_ord, int N) {
  int v = blockIdx.x * 256 + threadIdx.x;
  if (v >= N) return;
  u32 m = 0u;
  #pragma unroll
  for (int x = 0; x < NXCD; x++) {
    u32 t = m8[(size_t)x * N + v];
    m = (t > m) ? t : m;
  }
  m_ord[v] = m;
}

// exp(raw - max), f64 segment-sum in XCD-local copies (order noise ~1e-16,
// vanishes on f32 round; merge folds in fixed order)
__global__ __launch_bounds__(256)
void k_expsum8(const int* __restrict__ dst, const float* __restrict__ raw,
               const u32* __restrict__ m_ord, double* ss8, int N, int E) {
  int e = blockIdx.x * blockDim.x + threadIdx.x;
  if (e >= E) return;
  double* sW = ss8 + (size_t)xccid() * N;
  int d = dst[e];
  float ex = expf(raw[e] - inv_ordf(m_ord[d]));
  waddf64(&sW[d], (double)ex);
}

__global__ __launch_bounds__(256)
void k_ssmerge(const double* __restrict__ ss8, double* __restrict__ ssum, int N) {
  int v = blockIdx.x * 256 + threadIdx.x;
  if (v >= N) return;
  double s = 0.0;
  #pragma unroll
  for (int x = 0; x < NXCD; x++) s += ss8[(size_t)x * N + v];
  ssum[v] = s;
}

// frontier entry: .x = key = (~ord(score))<<32 | edge_id  (asc == desc score,
// stable index tiebreak), .y = (src<<32)|dst. Round-0 min-build fused here
// (complete before k_mpick<0> runs -> exact two-phase semantics).
__global__ __launch_bounds__(256)
void k_scorekey(const int* __restrict__ src, const int* __restrict__ dst,
                const float* __restrict__ raw, const u32* __restrict__ m_ord,
                const double* __restrict__ ssum,
                ulonglong2* __restrict__ front0, u64* nm8, int N, int E) {
  int e = blockIdx.x * blockDim.x + threadIdx.x;
  if (e >= E) return;
  u64* nmW = nm8 + (size_t)xccid() * N;
  int s = src[e], d = dst[e];
  float ex = expf(raw[e] - inv_ordf(m_ord[d]));
  float es = ex / (float)ssum[d] + 0.5f;
  u64 key = ((u64)(~ordf(es)) << 32) | (u32)e;
  u64 sd  = ((u64)(u32)s << 32) | (u32)d;
  front0[e] = make_ulonglong2(key, sd);
  wmin64(&nmW[s], key);
  if (d != s) wmin64(&nmW[d], key);
}

// fold 8 XCD-local copies -> nmOut (writes ALL N entries), re-arm nm8 to ~0
__global__ __launch_bounds__(256)
void k_merge(u64* nm8, u64* __restrict__ nmOut, int N) {
  int v = blockIdx.x * 256 + threadIdx.x;
  if (v >= N) return;
  u64 m = ~0ull;
  #pragma unroll
  for (int x = 0; x < NXCD; x++) {
    size_t idx = (size_t)x * N + v;
    u64 t = nm8[idx];
    if (t != ~0ull) { nm8[idx] = ~0ull; m = (t < m) ? t : m; }
  }
  nmOut[v] = m;
}

// min phase (heavy): XCD-local copies, local-L2 RMW
template<int R>
__global__ __launch_bounds__(256)
void k_mmin_h(const ulonglong2* __restrict__ fin, const u32* __restrict__ cntp,
              const u8* __restrict__ matched, u64* nm8, int N) {
  u32 cnt = *cntp;
  u64* nmW = nm8 + (size_t)xccid() * N;
  u32 nth = gridDim.x * 256;
  for (u32 i = blockIdx.x * 256 + threadIdx.x; i < cnt; i += nth) {
    ulonglong2 t = fin[i];
    int s = (int)(t.y >> 32), d = (int)(u32)t.y;
    if (matched[s] | matched[d]) continue;
    wmin64(&nmW[s], t.x);
    if (d != s) wmin64(&nmW[d], t.x);
  }
}

// min phase (light): small frontier, device-scope atomics are fine
template<int R>
__global__ __launch_bounds__(256)
void k_mmin_l(const ulonglong2* __restrict__ fin, const u32* __restrict__ cntp,
              const u8* __restrict__ matched, u64* nm) {
  u32 cnt = *cntp;
  u32 nth = gridDim.x * 256;
  for (u32 i = blockIdx.x * 256 + threadIdx.x; i < cnt; i += nth) {
    ulonglong2 t = fin[i];
    int s = (int)(t.y >> 32), d = (int)(u32)t.y;
    if (matched[s] | matched[d]) continue;
    atomicMin(&nm[s], t.x);
    if (d != s) atomicMin(&nm[d], t.x);
  }
}

// pick phase: min at BOTH endpoints -> matched (vertex-disjoint, keys unique);
// survivors compacted (1 atomic/block) + survivor-only reset of next nm buffer.
template<int R>
__global__ __launch_bounds__(256)
void k_mpick(const ulonglong2* __restrict__ fin, const u32* __restrict__ cntp,
             const u64* __restrict__ nm, u64* nmNext, u8* matched,
             ulonglong2* fout, u32* cntOut, ulonglong2* sortbuf, u32* scalars) {
  __shared__ u32 wb[4];
  __shared__ u32 bbase;
  u32 cnt = *cntp;
  int tx = threadIdx.x, lane = tx & 63, wid = tx >> 6;
  for (u32 base = blockIdx.x * 256; base < cnt; base += gridDim.x * 256) {
    u32 gid = base + tx;
    ulonglong2 t = make_ulonglong2(0ull, 0ull);
    int s = 0, d = 0;
    bool pk = false, surv = false;
    if (gid < cnt) {
      t = fin[gid];
      s = (int)(t.y >> 32); d = (int)(u32)t.y;
      if (!(matched[s] | matched[d])) {
        pk = (nm[s] == t.x) && (nm[d] == t.x);
        surv = !pk;
      }
    }
    // picks: wave-aggregated append (order fixed by later sort)
    u64 pm = __ballot(pk);
    if (pm) {
      u32 pre = (u32)__popcll(pm & ((1ull << lane) - 1ull));
      int ldr = __ffsll((long long)pm) - 1;
      u32 pb = 0;
      if (lane == ldr) pb = atomicAdd(&scalars[0], (u32)__popcll(pm));
      pb = __shfl(pb, ldr);
      if (pk) { matched[s] = 1; matched[d] = 1; sortbuf[pb + pre] = t; }
    }
    // survivors: block-aggregated compaction + next-round nm reset
    u64 sm = __ballot(surv);
    if (lane == 0) wb[wid] = (u32)__popcll(sm);
    __syncthreads();
    if (tx == 0) {
      u32 tt = wb[0] + wb[1] + wb[2] + wb[3];
      bbase = tt ? atomicAdd(cntOut, tt) : 0u;
    }
    __syncthreads();
    if (surv) {
      u32 woff = 0;
      for (int w = 0; w < wid; w++) woff += wb[w];
      u32 pre = (u32)__popcll(sm & ((1ull << lane) - 1ull));
      fout[bbase + woff + pre] = t;
      nmNext[s] = ~0ull;
      if (d != s) nmNext[d] = ~0ull;
    }
    __syncthreads();
  }
}

// single-block finish, 2-phase ping-pong rounds:
//   phase 1: min-build into nmCur (pre-reset at all live endpoints: grid round
//            NR-1 reset buffer 0 at surviving endpoints; in-loop, survivors
//            reset nmNext during phase 2)
//   phase 2: pick via atomic reads (L1 can't serve L2-atomic results);
//            survivors -> fout + reset nmNext
__global__ __launch_bounds__(1024)
void k_mfinish(ulonglong2* fA, ulonglong2* fB, u8* matched, u64* nmA, u64* nmB,
               ulonglong2* sortbuf, const u32* __restrict__ cntp, u32* scalars) {
  __shared__ u32 sh_cnt;
  u32 cnt = *cntp;
  int tx = threadIdx.x;
  ulonglong2* fin = fA; ulonglong2* fout = fB;
  u64* nmCur = nmA; u64* nmNxt = nmB;
  while (cnt > 0) {
    if (tx == 0) sh_cnt = 0;
    __syncthreads();
    for (u32 i = tx; i < cnt; i += 1024) {
      ulonglong2 t = fin[i];
      int s = (int)(t.y >> 32), d = (int)(u32)t.y;
      if (matched[s] | matched[d]) continue;
      wmin64(&nmCur[s], t.x);
      if (d != s) wmin64(&nmCur[d], t.x);
    }
    __syncthreads();
    for (u32 i = tx; i < cnt; i += 1024) {
      ulonglong2 t = fin[i];
      int s = (int)(t.y >> 32), d = (int)(u32)t.y;
      if (matched[s] | matched[d]) continue;
      u64 a = __hip_atomic_fetch_add(&nmCur[s], 0ull, __ATOMIC_RELAXED,
                                     __HIP_MEMORY_SCOPE_WORKGROUP);
      u64 b = (d == s) ? a
            : __hip_atomic_fetch_add(&nmCur[d], 0ull, __ATOMIC_RELAXED,
                                     __HIP_MEMORY_SCOPE_WORKGROUP);
      if (a == t.x && b == t.x) {
        matched[s] = 1; matched[d] = 1;
        u32 o = atomicAdd(&scalars[0], 1u);
        sortbuf[o] = t;
      } else {
        u32 o = atomicAdd(&sh_cnt, 1u);
        fout[o] = t;
        nmNxt[s] = ~0ull;
        if (d != s) nmNxt[d] = ~0ull;
      }
    }
    __syncthreads();
    cnt = sh_cnt;
    ulonglong2* tf = fin; fin = fout; fout = tf;
    u64* tn = nmCur; nmCur = nmNxt; nmNxt = tn;
    __syncthreads();
  }
}

// ---- bitonic sort of SORTN {key,sd} pairs by .x, as plain launches ----
__global__ __launch_bounds__(256)
void k_sort1(ulonglong2* buf) {
  __shared__ ulonglong2 t[STILE];
  const int base = blockIdx.x * STILE;
  for (int i = threadIdx.x; i < STILE; i += 256) t[i] = buf[base + i];
  __syncthreads();
  for (int k = 2; k <= STILE; k <<= 1) {
    for (int j = k >> 1; j > 0; j >>= 1) {
      for (int i = threadIdx.x; i < STILE; i += 256) {
        int p = i ^ j;
        if (p > i) {
          bool dir = (((base + i) & k) == 0);
          ulonglong2 a = t[i], c = t[p];
          if ((a.x > c.x) == dir) { t[i] = c; t[p] = a; }
        }
      }
      __syncthreads();
    }
  }
  for (int i = threadIdx.x; i < STILE; i += 256) buf[base + i] = t[i];
}

__global__ __launch_bounds__(256)
void k_gpass(ulonglong2* buf, int j, int k) {
  int i = blockIdx.x * 256 + threadIdx.x;
  int p = i ^ j;
  if (p > i && p < SORTN) {
    bool dir = ((i & k) == 0);
    ulonglong2 a = buf[i], c = buf[p];
    if ((a.x > c.x) == dir) { buf[i] = c; buf[p] = a; }
  }
}

__global__ __launch_bounds__(256)
void k_sortl(ulonglong2* buf, int k) {
  __shared__ ulonglong2 t[STILE];
  const int base = blockIdx.x * STILE;
  const bool dir = ((base & k) == 0);   // uniform per tile (k > STILE)
  for (int i = threadIdx.x; i < STILE; i += 256) t[i] = buf[base + i];
  __syncthreads();
  for (int j = STILE >> 1; j > 0; j >>= 1) {
    for (int i = threadIdx.x; i < STILE; i += 256) {
      int p = i ^ j;
      if (p > i) {
        ulonglong2 a = t[i], c = t[p];
        if ((a.x > c.x) == dir) { t[i] = c; t[p] = a; }
      }
    }
    __syncthreads();
  }
  for (int i = threadIdx.x; i < STILE; i += 256) buf[base + i] = t[i];
}

// sorted position i == cluster id; score recovered bit-exactly from the key
__global__ __launch_bounds__(256)
void k_assign(const ulonglong2* __restrict__ buf,
              int* cluster, int* memA, int* memB, float* scoreC,
              const u32* __restrict__ scalars) {
  int i = blockIdx.x * blockDim.x + threadIdx.x;
  if (i >= (int)scalars[0]) return;
  ulonglong2 t = buf[i];
  int s = (int)(t.y >> 32), d = (int)(u32)t.y;
  cluster[s] = i; cluster[d] = i;
  scoreC[i] = inv_ordf(~(u32)(t.x >> 32));
  memA[i] = s;
  memB[i] = (s == d) ? -1 : d;   // self-loop: single member
}

// exclusive scan of unmatched nodes -> trailing singleton cluster ids
__global__ __launch_bounds__(256)
void k_scan1(const u8* __restrict__ matched, u32* partials, int N) {
  __shared__ u32 sh[256];
  int b = blockIdx.x, tx = threadIdx.x;
  int v0 = b * 1024 + tx * 4;
  u32 c = 0;
  #pragma unroll
  for (int q = 0; q < 4; q++) { int v = v0 + q; if (v < N && !matched[v]) c++; }
  sh[tx] = c; __syncthreads();
  for (int s = 128; s > 0; s >>= 1) { if (tx < s) sh[tx] += sh[tx + s]; __syncthreads(); }
  if (tx == 0) partials[b] = sh[0];
}

__global__ void k_scan2(const u32* partials, u32* partials2, u32* scalars, int NB) {
  if (blockIdx.x == 0 && threadIdx.x == 0) {
    u32 run = 0;
    for (int i = 0; i < NB; i++) { partials2[i] = run; run += partials[i]; }
    scalars[1] = run;                 // total unmatched
    scalars[2] = scalars[0] + run;    // num_clusters
  }
}

__global__ __launch_bounds__(256)
void k_scan3(const u8* __restrict__ matched, const u32* __restrict__ partials2,
             const u32* __restrict__ scalars, int* cluster, int* memA, int* memB, int N) {
  __shared__ u32 sh[256];
  int b = blockIdx.x, tx = threadIdx.x;
  int v0 = b * 1024 + tx * 4;
  u32 f[4]; u32 c = 0;
  #pragma unroll
  for (int q = 0; q < 4; q++) { int v = v0 + q; f[q] = (v < N && !matched[v]); c += f[q]; }
  sh[tx] = c; __syncthreads();
  for (int s = 1; s < 256; s <<= 1) {      // Hillis-Steele inclusive scan
    u32 x = sh[tx];
    u32 y = (tx >= s) ? sh[tx - s] : 0;
    __syncthreads();
    sh[tx] = x + y;
    __syncthreads();
  }
  u32 base = scalars[0] + partials2[b] + (sh[tx] - c);
  #pragma unroll
  for (int q = 0; q < 4; q++) {
    if (f[q]) {
      int v = v0 + q;
      int cc = (int)base++;
      cluster[v] = cc; memA[cc] = v; memB[cc] = -1;
    }
  }
}

// new_x: wave per output row; <=2 members per cluster; zero tail rows
__global__ __launch_bounds__(256)
void k_newx(const float4* __restrict__ x4, const int* __restrict__ memA,
            const int* __restrict__ memB, const float* __restrict__ scoreC,
            const u32* __restrict__ scalars, float4* __restrict__ out4, int N) {
  int gt = blockIdx.x * blockDim.x + threadIdx.x;
  int w = gt >> 6, lane = gt & 63;
  if (w >= N) return;
  int nc = (int)scalars[2];
  float4 o;
  if (w < nc) {
    int a = memA[w], b = memB[w];
    float s = scoreC[w];
    float4 va = x4[(size_t)a * 64 + lane];
    float ox = va.x, oy = va.y, oz = va.z, ow = va.w;
    if (b >= 0) {
      float4 vb = x4[(size_t)b * 64 + lane];
      ox += vb.x; oy += vb.y; oz += vb.z; ow += vb.w;
    }
    o = make_float4(ox * s, oy * s, oz * s, ow * s);
  } else {
    o = make_float4(0.f, 0.f, 0.f, 0.f);
  }
  out4[(size_t)w * 64 + lane] = o;
}

// remap edges to cluster ids + emit batch zeros + num_clusters scalar
__global__ __launch_bounds__(256)
void k_remap(const int* __restrict__ ei, const int* __restrict__ cluster,
             float* __restrict__ outE, float* __restrict__ outB,
             const u32* __restrict__ scalars, int twoE, int N) {
  int i = blockIdx.x * blockDim.x + threadIdx.x;
  if (i < twoE) outE[i] = (float)cluster[ei[i]];
  int j = i - twoE;
  if (j >= 0 && j < N) outB[j] = 0.0f;        // batch is all zeros
  if (j == N) outB[N] = (float)scalars[2];    // num_clusters
}

// compile-time unrolled round launcher (distinct symbols per round)
template<int R>
static void launch_rounds(ulonglong2* frontA, ulonglong2* frontB, u64* nm8,
                          u64* node_min, u8* matched, ulonglong2* sortbuf,
                          u32* fcnt, u32* scalars, int N, int NB_E,
                          hipStream_t stream) {
  if constexpr (R < NR) {
    ulonglong2* fin  = (R & 1) ? frontB : frontA;
    ulonglong2* fout = (R & 1) ? frontA : frontB;
    u64* nm  = node_min + (size_t)(R & 1) * N;
    u64* nmN = node_min + (size_t)((R & 1) ^ 1) * N;
    int nbr = (R < 30) ? (NB_E >> R) : 0; if (nbr < 64) nbr = 64;
    if constexpr (R == 0) {
      // round-0 min map already built by k_scorekey + k_merge
    } else if constexpr (R < NHEAVY) {
      k_mmin_h<R><<<nbr, 256, 0, stream>>>(fin, fcnt + R, matched, nm8, N);
      k_merge<<<(N + 255) / 256, 256, 0, stream>>>(nm8, nm, N);
    } else {
      k_mmin_l<R><<<nbr, 256, 0, stream>>>(fin, fcnt + R, matched, nm);
    }
    k_mpick<R><<<nbr, 256, 0, stream>>>(fin, fcnt + R, nm, nmN, matched,
                                        fout, fcnt + R + 1, sortbuf, scalars);
    launch_rounds<R + 1>(frontA, frontB, nm8, node_min, matched, sortbuf,
                         fcnt, scalars, N, NB_E, stream);
  }
}

extern "C" void kernel_launch(void* const* d_in, const int* in_sizes, int n_in,
                              void* d_out, int out_size, void* d_ws, size_t ws_size,
                              hipStream_t stream) {
  const float* x    = (const float*)d_in[0];
  const int*   ei   = (const int*)d_in[1];
  const float* W    = (const float*)d_in[3];
  const float* bvec = (const float*)d_in[4];
  int N = in_sizes[2];
  int E = in_sizes[1] / 2;

  // workspace carve-out (~82 MB)
  char* p = (char*)d_ws;
  auto alloc = [&](size_t bytes) { char* r = p; p += (bytes + 255) & ~(size_t)255; return r; };
  float*      s_src    = (float*)alloc((size_t)N * 4);
  float*      s_dst    = (float*)alloc((size_t)N * 4);
  u32*        m_ord    = (u32*)alloc((size_t)N * 4);
  u32*        m8       = (u32*)alloc((size_t)NXCD * N * 4);
  double*     ssum     = (double*)alloc((size_t)N * 8);
  double*     ss8      = (double*)alloc((size_t)NXCD * N * 8);
  float*      raw      = (float*)alloc((size_t)E * 4);
  ulonglong2* frontA   = (ulonglong2*)alloc((size_t)E * 16);
  ulonglong2* frontB   = (ulonglong2*)alloc((size_t)E * 16);
  u8*         matched  = (u8*)alloc((size_t)N);
  u64*        node_min = (u64*)alloc((size_t)2 * N * 8);
  u64*        nm8      = (u64*)alloc((size_t)NXCD * N * 8);
  ulonglong2* sortbuf  = (ulonglong2*)alloc((size_t)SORTN * 16);
  int*        cluster  = (int*)alloc((size_t)N * 4);
  int*        memA     = (int*)alloc((size_t)N * 4);
  int*        memB     = (int*)alloc((size_t)N * 4);
  float*      scoreC   = (float*)alloc((size_t)N * 4);
  u32*        fcnt     = (u32*)alloc(1024);
  u32*        partials = (u32*)alloc(4096);
  u32*        partials2= (u32*)alloc(4096);
  u32*        scalars  = (u32*)alloc(256);
  (void)ws_size; (void)out_size; (void)n_in;

  const int* srcp = ei;
  const int* dstp = ei + E;
  float* out  = (float*)d_out;
  float* outX = out;
  float* outE = out + (size_t)N * 256;
  float* outB = outE + (size_t)2 * E;

  int NB_E = (E + 255) / 256;
  int cover = NXCD * N; if (cover < SORTN) cover = SORTN;
  k_init<<<(cover + 255) / 256, 256, 0, stream>>>(m_ord, m8, ssum, ss8, matched,
                                                  node_min, nm8, scoreC, sortbuf,
                                                  fcnt, scalars, N, E);
  k_dots<<<((size_t)N * 64 + 255) / 256, 256, 0, stream>>>(
      (const float4*)x, (const float4*)W, s_src, s_dst, N);
  k_max8<<<NB_E, 256, 0, stream>>>(srcp, dstp, s_src, s_dst, bvec, m8, raw, N, E);
  k_maxmerge<<<(N + 255) / 256, 256, 0, stream>>>(m8, m_ord, N);
  k_expsum8<<<NB_E, 256, 0, stream>>>(dstp, raw, m_ord, ss8, N, E);
  k_ssmerge<<<(N + 255) / 256, 256, 0, stream>>>(ss8, ssum, N);
  // scorekey also builds round-0 node-min in nm8 (XCD-local)
  k_scorekey<<<NB_E, 256, 0, stream>>>(srcp, dstp, raw, m_ord, ssum,
                                       frontA, nm8, N, E);
  k_merge<<<(N + 255) / 256, 256, 0, stream>>>(nm8, node_min, N);  // -> buffer 0

  launch_rounds<0>(frontA, frontB, nm8, node_min, matched, sortbuf, fcnt, scalars,
                   N, NB_E, stream);
  // NR even -> survivors in frontA; round NR-1 (odd) used buffer 1 as nm and
  // reset buffer 0 at surviving endpoints -> mfinish starts nmCur = buffer 0.
  k_mfinish<<<1, 1024, 0, stream>>>(frontA, frontB, matched,
                                    node_min, node_min + N,
                                    sortbuf, fcnt + NR, scalars);

  // sort chosen edges (bitonic over SORTN, plain launches)
  k_sort1<<<SORTN / STILE, 256, 0, stream>>>(sortbuf);
  for (int k = STILE << 1; k <= SORTN; k <<= 1) {
    for (int j = k >> 1; j >= STILE; j >>= 1)
      k_gpass<<<SORTN / 256, 256, 0, stream>>>(sortbuf, j, k);
    k_sortl<<<SORTN / STILE, 256, 0, stream>>>(sortbuf, k);
  }

  k_assign<<<SORTN / 256, 256, 0, stream>>>(sortbuf, cluster, memA, memB, scoreC, scalars);
  int NB = (N + 1023) / 1024;
  k_scan1<<<NB, 256, 0, stream>>>(matched, partials, N);
  k_scan2<<<1, 64, 0, stream>>>(partials, partials2, scalars, NB);
  k_scan3<<<NB, 256, 0, stream>>>(matched, partials2, scalars, cluster, memA, memB, N);

  k_newx<<<((size_t)N * 64 + 255) / 256, 256, 0, stream>>>(
      (const float4*)x, memA, memB, scoreC, scalars, (float4*)outX, N);
  k_remap<<<(2 * E + N + 1 + 255) / 256, 256, 0, stream>>>(
      ei, cluster, outE, outB, scalars, 2 * E, N);
}